// Round 6
// baseline (407.154 us; speedup 1.0000x reference)
//
#include <hip/hip_runtime.h>

// Problem constants (fixed by the reference's setup_inputs)
#define NN   100000      // nodes
#define EE   1600000     // num_edge
#define EROW 4800000     // edge_index row length (3*NUM_EDGE)

typedef _Float16 half8 __attribute__((ext_vector_type(8)));
typedef _Float16 half4 __attribute__((ext_vector_type(4)));
typedef float    f32x4 __attribute__((ext_vector_type(4)));

__device__ __forceinline__ float4 ld4(const float* p){ return *(const float4*)p; }

// Split fp32 -> (hi fp16) + (lo fp16, scaled by 2048). Packed lo16=hi, hi16=lo.
__device__ __forceinline__ unsigned splitf(float v) {
    _Float16 h = (_Float16)v;
    float r = v - (float)h;
    _Float16 l = (_Float16)(r * 2048.0f);
    union { _Float16 f; unsigned short u; } uh, ul;
    uh.f = h; ul.f = l;
    return (unsigned)uh.u | ((unsigned)ul.u << 16);
}

// ---------------------------------------------------------------------------
// Weight prep: split W_lin (256x256), W_lin2 (128x256), repacked W_fc1
// (128x128: row j = W_fc1[j&63][(j>>6)*128 ..]) into SEPARATE hi/lo fp16
// planes so B-fragments are direct 16-B global loads (L2-resident).
// ---------------------------------------------------------------------------
__global__ __launch_bounds__(256)
void prep_w(const float* __restrict__ W1, const float* __restrict__ W2,
            const float* __restrict__ W3,
            _Float16* __restrict__ o1h, _Float16* __restrict__ o1l,
            _Float16* __restrict__ o2h, _Float16* __restrict__ o2l,
            _Float16* __restrict__ o3h, _Float16* __restrict__ o3l)
{
    int idx = blockIdx.x * 256 + threadIdx.x;   // 448 blocks = 114688 threads
    float v; _Float16* ph; _Float16* pl; int o;
    if (idx < 65536) {
        v = W1[idx]; ph = o1h; pl = o1l; o = idx;
    } else if (idx < 98304) {
        o = idx - 65536; v = W2[o]; ph = o2h; pl = o2l;
    } else {
        o = idx - 98304;
        int j = o >> 7, k = o & 127;
        v = W3[(j & 63) * 256 + (j >> 6) * 128 + k]; ph = o3h; pl = o3l;
    }
    _Float16 h = (_Float16)v;
    ph[o] = h;
    pl[o] = (_Float16)((v - (float)h) * 2048.0f);
}

// ---------------------------------------------------------------------------
// MFMA split-fp16 GEMM: C[M x No] = A[M x K] @ B[No x K]^T (+epilogue).
// 256 thr = 4 waves, wave grid 2x2, wave tile 64x64 (4x4 of 16x16x32 f16).
// 3 MFMA passes: acc_hi += Ah*Bh; acc_mid += Ah*Bl + Al*Bh; C = hi + mid/2048.
// A staged via double-buffered LDS (41 KB, one barrier/kt); B-fragments read
// DIRECTLY from global hi/lo planes (weights are L2-resident; each 64-lane
// frag load touches 16 full cache lines -> fully coalesced).
// SRCA 0: A = trace fp32 (gathered 2-plane, split on the fly). 1: split plane.
// EPI  0: relu, store packed split. 1: row-L2-normalize, store packed split.
//      2: += b_fc1 on cols 0-63, store fp32 + fp16 copies.
// ---------------------------------------------------------------------------
template<int SRCA, int EPI>
__global__ __launch_bounds__(256, 2)
void gemm_mfma(const void* __restrict__ Asrc,
               const _Float16* __restrict__ Bhg, const _Float16* __restrict__ Blg,
               const float* __restrict__ bias, unsigned* __restrict__ outS,
               float* __restrict__ outF, unsigned short* __restrict__ outH,
               int M, int K, int No)
{
    // 40-halfword rows: 80 B stride (16B-aligned), 2-way (free) bank tiling.
    __shared__ __align__(16) _Float16 Ah[2][128][40];
    __shared__ __align__(16) _Float16 Al[2][128][40];
    // EPI==1 cross-wave row-ssq scratch aliases Ah after the K-loop.
    float* sqv = (float*)&Ah[0][0][0];   // viewed as [128][2]

    const int t     = threadIdx.x;
    const int wm    = (t >> 6) >> 1;   // wave m index (0..1)
    const int wn    = (t >> 6) & 1;    // wave n index (0..1)
    const int lane  = t & 63;
    const int lm    = lane & 15;
    const int q     = lane >> 4;
    const int mBase = blockIdx.x * 128;
    const int nBase = blockIdx.y * 128;

    const int srow = t >> 3;           // staging row 0..31 (+32*it)
    const int sseg = (t & 7) * 4;      // staging k-offset (elems)

    // B fragment base pointers: row = nBase + wn*64 + j*16 + lm, col q*8.
    const _Float16* bRowH = Bhg + (size_t)(nBase + wn * 64 + lm) * K + q * 8;
    const _Float16* bRowL = Blg + (size_t)(nBase + wn * 64 + lm) * K + q * 8;

    f32x4 aH[4][4], aM[4][4];
#pragma unroll
    for (int i = 0; i < 4; ++i)
#pragma unroll
        for (int j = 0; j < 4; ++j) {
            aH[i][j] = (f32x4){0.f, 0.f, 0.f, 0.f};
            aM[i][j] = (f32x4){0.f, 0.f, 0.f, 0.f};
        }

    uint2 sAh[4], sAl[4];

    auto loadStage = [&](int k0) {
#pragma unroll
        for (int it = 0; it < 4; ++it) {
            const int row = srow + it * 32;
            int rg = mBase + row; rg = rg < M ? rg : M - 1;
            if (SRCA == 0) {
                const int k = k0 + sseg;    // whole 32-chunk inside one L-plane
                const float* ap = (const float*)Asrc
                    + (size_t)(k >> 7) * ((size_t)NN * 128)
                    + (size_t)rg * 128 + (k & 127);
                float4 f = ld4(ap);
                unsigned p0 = splitf(f.x), p1 = splitf(f.y);
                unsigned p2 = splitf(f.z), p3 = splitf(f.w);
                sAh[it].x = (p0 & 0xffffu) | (p1 << 16);
                sAh[it].y = (p2 & 0xffffu) | (p3 << 16);
                sAl[it].x = (p0 >> 16) | (p1 & 0xffff0000u);
                sAl[it].y = (p2 >> 16) | (p3 & 0xffff0000u);
            } else {
                const unsigned* ap = (const unsigned*)Asrc + (size_t)rg * K + k0 + sseg;
                uint4 u = *(const uint4*)ap;
                sAh[it].x = (u.x & 0xffffu) | (u.y << 16);
                sAh[it].y = (u.z & 0xffffu) | (u.w << 16);
                sAl[it].x = (u.x >> 16) | (u.y & 0xffff0000u);
                sAl[it].y = (u.z >> 16) | (u.w & 0xffff0000u);
            }
        }
    };

    loadStage(0);
    const int nk = K / 32;
    for (int kt = 0; kt < nk; ++kt) {
        const int b = kt & 1;
        // Write staged regs -> LDS[b]. Safe without a leading barrier: any
        // wave still reading buffer b is at iteration kt-2, separated from
        // this write by the kt-1 barrier it must pass after its reads.
#pragma unroll
        for (int it = 0; it < 4; ++it) {
            const int row = srow + it * 32;
            *(uint2*)&Ah[b][row][sseg] = sAh[it];
            *(uint2*)&Al[b][row][sseg] = sAl[it];
        }
        __syncthreads();
        if (kt + 1 < nk) loadStage((kt + 1) * 32);   // prefetch during MFMA

        // B fragments: direct global loads (L2-hit), issued first.
        half8 fBh[4], fBl[4];
#pragma unroll
        for (int j = 0; j < 4; ++j) {
            fBh[j] = *(const half8*)(bRowH + (size_t)j * 16 * K + kt * 32);
            fBl[j] = *(const half8*)(bRowL + (size_t)j * 16 * K + kt * 32);
        }
        half8 fAh[4], fAl[4];
#pragma unroll
        for (int i = 0; i < 4; ++i) {
            fAh[i] = *(const half8*)&Ah[b][wm * 64 + i * 16 + lm][q * 8];
            fAl[i] = *(const half8*)&Al[b][wm * 64 + i * 16 + lm][q * 8];
        }
#pragma unroll
        for (int i = 0; i < 4; ++i)
#pragma unroll
            for (int j = 0; j < 4; ++j)
                aH[i][j] = __builtin_amdgcn_mfma_f32_16x16x32_f16(fAh[i], fBh[j], aH[i][j], 0, 0, 0);
#pragma unroll
        for (int i = 0; i < 4; ++i)
#pragma unroll
            for (int j = 0; j < 4; ++j)
                aM[i][j] = __builtin_amdgcn_mfma_f32_16x16x32_f16(fAh[i], fBl[j], aM[i][j], 0, 0, 0);
#pragma unroll
        for (int i = 0; i < 4; ++i)
#pragma unroll
            for (int j = 0; j < 4; ++j)
                aM[i][j] = __builtin_amdgcn_mfma_f32_16x16x32_f16(fAl[i], fBh[j], aM[i][j], 0, 0, 0);
    }

    // Combine split accumulators: C = hi + mid/2048
    const float cM = 1.0f / 2048.0f;
#pragma unroll
    for (int i = 0; i < 4; ++i)
#pragma unroll
        for (int j = 0; j < 4; ++j)
            aH[i][j] = aH[i][j] + aM[i][j] * cM;

    float nm[4][4];
    if (EPI == 1) {
        __syncthreads();   // all frag reads done before aliasing Ah as sqv
#pragma unroll
        for (int i = 0; i < 4; ++i)
#pragma unroll
            for (int r = 0; r < 4; ++r) {
                float s = 0.f;
#pragma unroll
                for (int j = 0; j < 4; ++j) { float x = aH[i][j][r]; s = fmaf(x, x, s); }
#pragma unroll
                for (int off = 1; off < 16; off <<= 1) s += __shfl_xor(s, off, 16);
                if (lm == 0) sqv[(wm * 64 + i * 16 + q * 4 + r) * 2 + wn] = s;
            }
        __syncthreads();
#pragma unroll
        for (int i = 0; i < 4; ++i)
#pragma unroll
            for (int r = 0; r < 4; ++r) {
                const int rl = wm * 64 + i * 16 + q * 4 + r;
                nm[i][r] = fmaxf(sqrtf(sqv[rl * 2] + sqv[rl * 2 + 1]), 1e-12f);
            }
    }

    float bj[4] = {0.f, 0.f, 0.f, 0.f};
    if (EPI == 2 && wn == 0) {
#pragma unroll
        for (int j = 0; j < 4; ++j) bj[j] = bias[j * 16 + lm];
    }

#pragma unroll
    for (int i = 0; i < 4; ++i)
#pragma unroll
        for (int r = 0; r < 4; ++r) {
            const int m = mBase + wm * 64 + i * 16 + q * 4 + r;
            if (m < M) {
#pragma unroll
                for (int j = 0; j < 4; ++j) {
                    const int c = nBase + wn * 64 + j * 16 + lm;
                    float v = aH[i][j][r];
                    if (EPI == 0) { v = fmaxf(v, 0.f); outS[(size_t)m * No + c] = splitf(v); }
                    if (EPI == 1) { v = v / nm[i][r];  outS[(size_t)m * No + c] = splitf(v); }
                    if (EPI == 2) {
                        v += bj[j];
                        outF[(size_t)m * No + c] = v;
                        union { _Float16 f; unsigned short u; } cv; cv.f = (_Float16)v;
                        outH[(size_t)m * No + c] = cv.u;
                    }
                }
            }
        }
}

// ---------------------------------------------------------------------------
// Edge kernel: 128 edges/block, 16 lanes/edge, 8 edges/lane-group.
// fp16 gather primary path; certified bound -> rare exact fp32 re-gather.
// ---------------------------------------------------------------------------
#define EPB 128
__global__ __launch_bounds__(256, 4)
void edge_k(const unsigned short* __restrict__ pH, const float* __restrict__ p,
            const int* __restrict__ ei, const float* __restrict__ gum,
            const float* __restrict__ W2, const float* __restrict__ b2,
            float* __restrict__ out)
{
    __shared__ int   sidx[EPB];
    __shared__ int   didx[EPB];
    __shared__ float gl[2 * EPB];
    __shared__ float act[EPB];

    const int t  = threadIdx.x;
    const int e0 = blockIdx.x * EPB;

    if (t < EPB) sidx[t] = ei[e0 + t];
    else         didx[t - EPB] = ei[EROW + e0 + (t - EPB)];
    gl[t] = gum[(size_t)e0 * 2 + t];
    __syncthreads();

    const int j   = t & 15;
    const int grp = t >> 4;
    const float4 w0 = ld4(&W2[j * 4]);
    const float4 w1 = ld4(&W2[64 + j * 4]);
    const float4 dw = make_float4(fabsf(w0.x - w1.x), fabsf(w0.y - w1.y),
                                  fabsf(w0.z - w1.z), fabsf(w0.w - w1.w));
    const float b20 = b2[0], b21 = b2[1];

    union U8 { uint2 u; half4 h; };
    U8 ua[8], ub[8];
#pragma unroll
    for (int it = 0; it < 8; ++it) {
        const int el = grp * 8 + it;
        ua[it].u = *(const uint2*)&pH[(size_t)sidx[el] * 128 + j * 4];
        ub[it].u = *(const uint2*)&pH[(size_t)didx[el] * 128 + 64 + j * 4];
    }

#pragma unroll
    for (int it = 0; it < 8; ++it) {
        const int el = grp * 8 + it;
        const float a0 = (float)ua[it].h[0], a1 = (float)ua[it].h[1];
        const float a2 = (float)ua[it].h[2], a3 = (float)ua[it].h[3];
        const float c0 = (float)ub[it].h[0], c1 = (float)ub[it].h[1];
        const float c2 = (float)ub[it].h[2], c3 = (float)ub[it].h[3];
        const float r0 = fmaxf(a0 + c0, 0.f);
        const float r1 = fmaxf(a1 + c1, 0.f);
        const float r2 = fmaxf(a2 + c2, 0.f);
        const float r3 = fmaxf(a3 + c3, 0.f);
        float s0 = r0 * w0.x + r1 * w0.y + r2 * w0.z + r3 * w0.w;
        float s1 = r0 * w1.x + r1 * w1.y + r2 * w1.z + r3 * w1.w;
        float eb = dw.x * (fabsf(a0) + fabsf(c0)) + dw.y * (fabsf(a1) + fabsf(c1))
                 + dw.z * (fabsf(a2) + fabsf(c2)) + dw.w * (fabsf(a3) + fabsf(c3));
#pragma unroll
        for (int off = 1; off < 16; off <<= 1) {
            s0 += __shfl_xor(s0, off, 16);
            s1 += __shfl_xor(s1, off, 16);
            eb += __shfl_xor(eb, off, 16);
        }
        const float g0 = gl[el * 2], g1 = gl[el * 2 + 1];
        const float gap = (s0 + b20 + g0) - (s1 + b21 + g1);
        const float bound = eb * 0.0009765625f + 2e-5f;   // 2^-10 * eb + slack
        float av;
        if (fabsf(gap) > bound) {
            av = (gap >= 0.f) ? 1.f : 0.f;
        } else {
            const float4 pa = ld4(&p[(size_t)sidx[el] * 128 + j * 4]);
            const float4 pb = ld4(&p[(size_t)didx[el] * 128 + 64 + j * 4]);
            const float q0 = fmaxf(pa.x + pb.x, 0.f);
            const float q1 = fmaxf(pa.y + pb.y, 0.f);
            const float q2 = fmaxf(pa.z + pb.z, 0.f);
            const float q3 = fmaxf(pa.w + pb.w, 0.f);
            float t0 = q0 * w0.x + q1 * w0.y + q2 * w0.z + q3 * w0.w;
            float t1 = q0 * w1.x + q1 * w1.y + q2 * w1.z + q3 * w1.w;
#pragma unroll
            for (int off = 1; off < 16; off <<= 1) {
                t0 += __shfl_xor(t0, off, 16);
                t1 += __shfl_xor(t1, off, 16);
            }
            const float ge = (t0 + b20 + g0) - (t1 + b21 + g1);
            av = (ge >= 0.f) ? 1.f : 0.f;
        }
        if (j == 0) act[el] = av;
    }
    __syncthreads();

    if (t < EPB) {
        const float a = act[t];
        const size_t e = (size_t)e0 + t;
        out[e]                  = a;
        out[EE + e]             = 1.f - a;
        out[2 * (size_t)EE + e] = 1.f - a;
    }
}

// ---------------------------------------------------------------------------
extern "C" void kernel_launch(void* const* d_in, const int* in_sizes, int n_in,
                              void* d_out, int out_size, void* d_ws, size_t ws_size,
                              hipStream_t stream)
{
    const float* trace  = (const float*)d_in[0];   // (2,100000,128)
    const float* W_lin  = (const float*)d_in[1];   // (256,256)
    const float* W_lin2 = (const float*)d_in[2];   // (128,256)
    const float* W_fc1  = (const float*)d_in[3];   // (64,256)
    const float* b_fc1  = (const float*)d_in[4];   // (64,)
    const float* W_fc2  = (const float*)d_in[5];   // (2,64)
    const float* b_fc2  = (const float*)d_in[6];   // (2,)
    const float* gum    = (const float*)d_in[7];   // (1600000,2)
    const int*   ei     = (const int*)  d_in[8];   // (2,4800000)
    float*       out    = (float*)d_out;           // (4800000,)

    // Workspace (same 154 MB footprint as R5): h packed [NN x 256 dw] at 0
    // (102.4 MB); mvc packed [NN x 128 dw] (51.2 MB); weight hi/lo planes
    // (0.45 MB). p (fp32) and pH (fp16) overlay h's region (h dead after
    // GEMM2; GEMM2 completes before GEMM3 starts - stream-serialized).
    char* ws = (char*)d_ws;
    unsigned*       hpl = (unsigned*)ws;
    unsigned*       mpl = (unsigned*)(ws + (size_t)NN * 256 * 4);
    _Float16*       W1h = (_Float16*)(ws + (size_t)NN * 256 * 4 + (size_t)NN * 128 * 4);
    _Float16*       W1l = W1h + 65536;
    _Float16*       W2h = W1l + 65536;
    _Float16*       W2l = W2h + 32768;
    _Float16*       W3h = W2l + 32768;
    _Float16*       W3l = W3h + 16384;
    float*          p   = (float*)ws;                                  // 51.2 MB
    unsigned short* pH  = (unsigned short*)(ws + (size_t)NN * 128 * 4); // +25.6 MB

    prep_w<<<448, 256, 0, stream>>>(W_lin, W_lin2, W_fc1, W1h, W1l, W2h, W2l, W3h, W3l);

    const int mB = (NN + 127) / 128;   // 782

    // h = relu(x @ W_lin^T), stored packed split
    gemm_mfma<0, 0><<<dim3(mB, 2), 256, 0, stream>>>(trace, W1h, W1l, nullptr, hpl, nullptr, nullptr, NN, 256, 256);
    // mvc = normalize_rows(h @ W_lin2^T), stored packed split
    gemm_mfma<1, 1><<<dim3(mB, 1), 256, 0, stream>>>(hpl, W2h, W2l, nullptr, mpl, nullptr, nullptr, NN, 256, 128);
    // p[n] = [W_fc1_left @ mvcn + b_fc1 | W_fc1_right @ mvcn], fp32 + fp16
    gemm_mfma<1, 2><<<dim3(mB, 1), 256, 0, stream>>>(mpl, W3h, W3l, b_fc1, nullptr, p, pH, NN, 128, 128);
    // per-edge score + hard mask (fp16 fast path, certified fp32 fallback)
    edge_k<<<EE / EPB, 256, 0, stream>>>(pH, p, ei, gum, W_fc2, b_fc2, out);
}